// Round 1
// 3918.739 us; speedup vs baseline: 1.7407x; 1.7407x over previous
//
#include <hip/hip_runtime.h>
#include <hip/hip_bf16.h>
#include <math.h>

#define VV 50257
#define SS 1024
#define BB 2
#define DD 768
#define HH 12
#define HDIM 64
#define FF 3072
#define LL 2
#define NT (BB*SS)   // 2048 tokens

typedef _Float16 half4_t __attribute__((ext_vector_type(4)));
typedef _Float16 half8_t __attribute__((ext_vector_type(8)));
typedef float   float4_t __attribute__((ext_vector_type(4)));

// ---------------------------------------------------------------- embedding
__global__ void embed_kernel(const int* __restrict__ idx,
                             const float* __restrict__ tok,
                             const float* __restrict__ pos,
                             float* __restrict__ x) {
    int i = blockIdx.x;            // token index [0, NT)
    int t = idx[i];
    int s = i % SS;
    const float* tr = tok + (size_t)t * DD;
    const float* pr = pos + (size_t)s * DD;
    float* xr = x + (size_t)i * DD;
    for (int d = threadIdx.x; d < DD; d += blockDim.x)
        xr[d] = tr[d] + pr[d];
}

// ---------------------------------------------------------------- layernorm
__inline__ __device__ float wave_reduce_sum(float v) {
    #pragma unroll
    for (int o = 32; o > 0; o >>= 1) v += __shfl_down(v, o);
    return v;
}

__global__ void ln_kernel(const float* __restrict__ x,
                          const float* __restrict__ w,
                          const float* __restrict__ b,
                          float* __restrict__ out) {
    int i = blockIdx.x;
    const float* xr = x + (size_t)i * DD;
    float s = 0.f, ss = 0.f;
    for (int d = threadIdx.x; d < DD; d += blockDim.x) {
        float v = xr[d];
        s += v; ss += v * v;
    }
    __shared__ float sred[8];
    __shared__ float smean, srstd;
    int wid = threadIdx.x >> 6, lane = threadIdx.x & 63;
    float rs = wave_reduce_sum(s);
    float rss = wave_reduce_sum(ss);
    if (lane == 0) { sred[wid] = rs; sred[4 + wid] = rss; }
    __syncthreads();
    if (threadIdx.x == 0) {
        float ts = 0.f, tss = 0.f;
        #pragma unroll
        for (int k = 0; k < 4; k++) { ts += sred[k]; tss += sred[4 + k]; }
        float m = ts / DD;
        float var = tss / DD - m * m;
        smean = m;
        srstd = rsqrtf(var + 1e-5f);
    }
    __syncthreads();
    float m = smean, r = srstd;
    float* orow = out + (size_t)i * DD;
    for (int d = threadIdx.x; d < DD; d += blockDim.x)
        orow[d] = (xr[d] - m) * r * w[d] + b[d];
}

// ---------------------------------------------------------------- GELU
__device__ __forceinline__ float gelu_f(float z) {
    const float c = 0.7978845608028654f; // sqrt(2/pi)
    float t = tanhf(c * (z + 0.044715f * z * z * z));
    return 0.5f * z * (1.0f + t);
}

// ---------------------------------------------------------------- GEMM NN
// C[M,Nn] = A[M,K] @ W[K,Nn] + bias (+ gelu) (+ residual)
// Tile 64x64, BK=16, 256 threads, 4x4 per thread. M,Nn,K multiples of 64/16.
template<int ACT, bool RES>
__global__ void gemm_nn(const float* __restrict__ A,
                        const float* __restrict__ W,
                        const float* __restrict__ bias,
                        const float* __restrict__ resid,
                        float* __restrict__ C,
                        int M, int Nn, int K) {
    __shared__ float As[16][65];
    __shared__ float Ws[16][65];
    const int bm = blockIdx.y * 64;
    const int bn = blockIdx.x * 64;
    const int tid = threadIdx.x;
    const int tx = tid & 15, ty = tid >> 4;
    float acc[4][4] = {};
    for (int k0 = 0; k0 < K; k0 += 16) {
        #pragma unroll
        for (int r = 0; r < 4; r++) {
            int e = tid + 256 * r;
            int m = e >> 4, kk = e & 15;
            As[kk][m] = A[(size_t)(bm + m) * K + k0 + kk];
        }
        #pragma unroll
        for (int r = 0; r < 4; r++) {
            int e = tid + 256 * r;
            int kk = e >> 6, n = e & 63;
            Ws[kk][n] = W[(size_t)(k0 + kk) * Nn + bn + n];
        }
        __syncthreads();
        #pragma unroll
        for (int kk = 0; kk < 16; kk++) {
            float a[4], wv4[4];
            #pragma unroll
            for (int ii = 0; ii < 4; ii++) a[ii] = As[kk][ty * 4 + ii];
            #pragma unroll
            for (int jj = 0; jj < 4; jj++) wv4[jj] = Ws[kk][tx * 4 + jj];
            #pragma unroll
            for (int ii = 0; ii < 4; ii++)
                #pragma unroll
                for (int jj = 0; jj < 4; jj++)
                    acc[ii][jj] += a[ii] * wv4[jj];
        }
        __syncthreads();
    }
    #pragma unroll
    for (int ii = 0; ii < 4; ii++) {
        int row = bm + ty * 4 + ii;
        #pragma unroll
        for (int jj = 0; jj < 4; jj++) {
            int col = bn + tx * 4 + jj;
            float v = acc[ii][jj] + bias[col];
            if (ACT == 1) v = gelu_f(v);
            if (RES) v += resid[(size_t)row * Nn + col];
            C[(size_t)row * Nn + col] = v;
        }
    }
}

// ---------------------------------------------------------------- GEMM NT (LM head, f16 MFMA)
// C[M,Nn] = A[M,K] @ Bm[Nn,K]^T ; fp32 in/out, fp16 MFMA compute (fp32 accum).
// 128x128 tile, BK=32, 256 threads = 4 waves in 2x2; each wave owns 64x64
// (4x4 fragments of 16x16x32). LDS rows padded to 40 halves (80 B = 20 banks)
// -> fragment ds_read_b64 pairs alias 2-way (free, m136).
// Bm rows (vocab) guarded: gn >= Nn stages zeros; C store guarded on col.
__global__ __launch_bounds__(256) void gemm_nt_f16(const float* __restrict__ A,
                                                   const float* __restrict__ Bm,
                                                   float* __restrict__ C,
                                                   int M, int Nn, int K) {
    __shared__ half4_t As4[128 * 10];   // [row][40 halves] as half4 units
    __shared__ half4_t Bs4[128 * 10];
    const int bm = blockIdx.y * 128;
    const int bn = blockIdx.x * 128;
    const int tid = threadIdx.x;
    const int lane = tid & 63;
    const int wave = tid >> 6;
    const int wr = (wave >> 1) * 64;     // wave row offset in tile
    const int wc = (wave & 1) * 64;      // wave col offset in tile
    const int lrow = lane & 15;
    const int kb2 = (lane >> 4) * 2;     // half4 unit index of this lane's k-chunk

    const int srow = tid >> 3;           // staging: 8 float4 per row of 32 floats
    const int sc4 = tid & 7;

    float4_t acc[4][4];
    #pragma unroll
    for (int m = 0; m < 4; m++)
        #pragma unroll
        for (int n = 0; n < 4; n++)
            acc[m][n] = 0.f;

    for (int k0 = 0; k0 < K; k0 += 32) {
        // ---- stage A,B tiles: fp32 global -> fp16 LDS
        #pragma unroll
        for (int p = 0; p < 4; p++) {
            int row = srow + p * 32;
            float4_t va = *(const float4_t*)(A + (size_t)(bm + row) * K + k0 + sc4 * 4);
            half4_t ha;
            ha[0] = (_Float16)va[0]; ha[1] = (_Float16)va[1];
            ha[2] = (_Float16)va[2]; ha[3] = (_Float16)va[3];
            As4[row * 10 + sc4] = ha;
            int gn = bn + row;
            float4_t vb = 0.f;
            if (gn < Nn)
                vb = *(const float4_t*)(Bm + (size_t)gn * K + k0 + sc4 * 4);
            half4_t hb;
            hb[0] = (_Float16)vb[0]; hb[1] = (_Float16)vb[1];
            hb[2] = (_Float16)vb[2]; hb[3] = (_Float16)vb[3];
            Bs4[row * 10 + sc4] = hb;
        }
        __syncthreads();
        // ---- fragment loads + MFMA
        half8_t af[4], bf[4];
        #pragma unroll
        for (int m = 0; m < 4; m++) {
            int r = wr + m * 16 + lrow;
            half4_t lo = As4[r * 10 + kb2];
            half4_t hi = As4[r * 10 + kb2 + 1];
            af[m] = __builtin_shufflevector(lo, hi, 0, 1, 2, 3, 4, 5, 6, 7);
        }
        #pragma unroll
        for (int n = 0; n < 4; n++) {
            int r = wc + n * 16 + lrow;
            half4_t lo = Bs4[r * 10 + kb2];
            half4_t hi = Bs4[r * 10 + kb2 + 1];
            bf[n] = __builtin_shufflevector(lo, hi, 0, 1, 2, 3, 4, 5, 6, 7);
        }
        #pragma unroll
        for (int m = 0; m < 4; m++)
            #pragma unroll
            for (int n = 0; n < 4; n++)
                acc[m][n] = __builtin_amdgcn_mfma_f32_16x16x32_f16(af[m], bf[n], acc[m][n], 0, 0, 0);
        __syncthreads();
    }

    // ---- epilogue: C/D layout col=lane&15, row=(lane>>4)*4+reg (m89-verified)
    const int rbase = bm + wr + (lane >> 4) * 4;
    const int cbase = bn + wc + lrow;
    #pragma unroll
    for (int m = 0; m < 4; m++) {
        #pragma unroll
        for (int n = 0; n < 4; n++) {
            int col = cbase + n * 16;
            if (col < Nn) {
                #pragma unroll
                for (int r = 0; r < 4; r++) {
                    int row = rbase + m * 16 + r;
                    C[(size_t)row * Nn + col] = acc[m][n][r];
                }
            }
        }
    }
}

// ---------------------------------------------------------------- attention
// One wave (64 threads) per (q-position, b*h). Scores in LDS, masked softmax,
// then PV accumulate with lane = head-dim.
__global__ void attn_kernel(const float* __restrict__ q,
                            const float* __restrict__ k,
                            const float* __restrict__ v,
                            float* __restrict__ out) {
    const int sq = blockIdx.x;
    const int bh = blockIdx.y;
    const int b = bh / HH, h = bh % HH;
    const int lane = threadIdx.x;
    __shared__ float qs[HDIM];
    __shared__ float sc[SS];
    const size_t base = (size_t)b * SS * DD + (size_t)h * HDIM;
    qs[lane] = q[base + (size_t)sq * DD + lane];
    __syncthreads();
    const float scale = 0.125f; // 1/sqrt(64)
    const int nk = sq + 1;
    for (int j0 = 0; j0 < nk; j0 += 64) {
        int j = j0 + lane;
        if (j < nk) {
            const float* kr = k + base + (size_t)j * DD;
            float acc = 0.f;
            #pragma unroll
            for (int d = 0; d < HDIM; d++) acc += qs[d] * kr[d];
            sc[j] = acc * scale;
        }
    }
    __syncthreads();
    float m = -1e30f;
    for (int j = lane; j < nk; j += 64) m = fmaxf(m, sc[j]);
    #pragma unroll
    for (int o = 32; o > 0; o >>= 1) m = fmaxf(m, __shfl_down(m, o));
    m = __shfl(m, 0);
    float ssum = 0.f;
    for (int j = lane; j < nk; j += 64) {
        float e = __expf(sc[j] - m);
        sc[j] = e;
        ssum += e;
    }
    #pragma unroll
    for (int o = 32; o > 0; o >>= 1) ssum += __shfl_down(ssum, o);
    ssum = __shfl(ssum, 0);
    const float inv = 1.0f / ssum;
    __syncthreads();
    float oacc = 0.f;
    for (int j = 0; j < nk; j++)
        oacc += sc[j] * v[base + (size_t)j * DD + lane];
    out[base + (size_t)sq * DD + lane] = oacc * inv;
}

// ---------------------------------------------------------------- launch
extern "C" void kernel_launch(void* const* d_in, const int* in_sizes, int n_in,
                              void* d_out, int out_size, void* d_ws, size_t ws_size,
                              hipStream_t stream) {
    const int*   word_idx = (const int*)  d_in[0];
    const float* tok_emb  = (const float*)d_in[1];
    const float* pos_emb  = (const float*)d_in[2];
    const float* ln1_w    = (const float*)d_in[3];
    const float* ln1_b    = (const float*)d_in[4];
    const float* wq       = (const float*)d_in[5];
    const float* bq       = (const float*)d_in[6];
    const float* wk       = (const float*)d_in[7];
    const float* bk       = (const float*)d_in[8];
    const float* wv       = (const float*)d_in[9];
    const float* bv       = (const float*)d_in[10];
    const float* wo       = (const float*)d_in[11];
    const float* bo       = (const float*)d_in[12];
    const float* ln2_w    = (const float*)d_in[13];
    const float* ln2_b    = (const float*)d_in[14];
    const float* w1       = (const float*)d_in[15];
    const float* b1       = (const float*)d_in[16];
    const float* w2       = (const float*)d_in[17];
    const float* b2       = (const float*)d_in[18];
    const float* lnf_w    = (const float*)d_in[19];
    const float* lnf_b    = (const float*)d_in[20];
    float* out = (float*)d_out;

    float* x   = (float*)d_ws;
    float* hbf = x   + (size_t)NT * DD;
    float* qb  = hbf + (size_t)NT * DD;
    float* kb  = qb  + (size_t)NT * DD;
    float* vb  = kb  + (size_t)NT * DD;
    float* att = vb  + (size_t)NT * DD;
    float* mid = att + (size_t)NT * DD;   // NT x FF

    embed_kernel<<<NT, 256, 0, stream>>>(word_idx, tok_emb, pos_emb, x);

    dim3 g_dd(DD / 64, NT / 64);     // 12 x 32
    dim3 g_df(FF / 64, NT / 64);     // 48 x 32

    for (int l = 0; l < LL; l++) {
        const float* wq_l = wq + (size_t)l * DD * DD;
        const float* wk_l = wk + (size_t)l * DD * DD;
        const float* wv_l = wv + (size_t)l * DD * DD;
        const float* wo_l = wo + (size_t)l * DD * DD;
        const float* w1_l = w1 + (size_t)l * DD * FF;
        const float* w2_l = w2 + (size_t)l * FF * DD;

        ln_kernel<<<NT, 256, 0, stream>>>(x, ln1_w + l * DD, ln1_b + l * DD, hbf);
        gemm_nn<0, false><<<g_dd, 256, 0, stream>>>(hbf, wq_l, bq + l * DD, nullptr, qb, NT, DD, DD);
        gemm_nn<0, false><<<g_dd, 256, 0, stream>>>(hbf, wk_l, bk + l * DD, nullptr, kb, NT, DD, DD);
        gemm_nn<0, false><<<g_dd, 256, 0, stream>>>(hbf, wv_l, bv + l * DD, nullptr, vb, NT, DD, DD);
        attn_kernel<<<dim3(SS, BB * HH), 64, 0, stream>>>(qb, kb, vb, att);
        gemm_nn<0, true><<<g_dd, 256, 0, stream>>>(att, wo_l, bo + l * DD, x, x, NT, DD, DD);
        ln_kernel<<<NT, 256, 0, stream>>>(x, ln2_w + l * DD, ln2_b + l * DD, hbf);
        gemm_nn<1, false><<<g_df, 256, 0, stream>>>(hbf, w1_l, b1 + l * FF, nullptr, mid, NT, FF, DD);
        gemm_nn<0, true><<<g_dd, 256, 0, stream>>>(mid, w2_l, b2 + l * DD, x, x, NT, DD, FF);
    }

    ln_kernel<<<NT, 256, 0, stream>>>(x, lnf_w, lnf_b, hbf);
    gemm_nt_f16<<<dim3((VV + 127) / 128, NT / 128), 256, 0, stream>>>(hbf, tok_emb, out, NT, VV, DD);
}

// Round 2
// 1607.605 us; speedup vs baseline: 4.2432x; 2.4376x over previous
//
#include <hip/hip_runtime.h>
#include <math.h>

#define VV 50257
#define SS 1024
#define BB 2
#define DD 768
#define HH 12
#define HDIM 64
#define FF 3072
#define LL 2
#define NT (BB*SS)     // 2048 tokens
#define QKV_LD 2304    // fused q|k|v row stride

typedef _Float16 half4_t __attribute__((ext_vector_type(4)));
typedef _Float16 half8_t __attribute__((ext_vector_type(8)));
typedef float   float4_t __attribute__((ext_vector_type(4)));

// ---------------------------------------------------------------- embedding
__global__ void embed_kernel(const int* __restrict__ idx,
                             const float* __restrict__ tok,
                             const float* __restrict__ pos,
                             float* __restrict__ x) {
    int i = blockIdx.x;
    int t = idx[i];
    int s = i % SS;
    const float* tr = tok + (size_t)t * DD;
    const float* pr = pos + (size_t)s * DD;
    float* xr = x + (size_t)i * DD;
    for (int d = threadIdx.x; d < DD; d += blockDim.x)
        xr[d] = tr[d] + pr[d];
}

// ---------------------------------------------------------------- layernorm
__inline__ __device__ float wave_reduce_sum(float v) {
    #pragma unroll
    for (int o = 32; o > 0; o >>= 1) v += __shfl_down(v, o);
    return v;
}

__global__ void ln_kernel(const float* __restrict__ x,
                          const float* __restrict__ w,
                          const float* __restrict__ b,
                          float* __restrict__ out) {
    int i = blockIdx.x;
    const float* xr = x + (size_t)i * DD;
    float s = 0.f, ss = 0.f;
    for (int d = threadIdx.x; d < DD; d += blockDim.x) {
        float v = xr[d];
        s += v; ss += v * v;
    }
    __shared__ float sred[8];
    __shared__ float smean, srstd;
    int wid = threadIdx.x >> 6, lane = threadIdx.x & 63;
    float rs = wave_reduce_sum(s);
    float rss = wave_reduce_sum(ss);
    if (lane == 0) { sred[wid] = rs; sred[4 + wid] = rss; }
    __syncthreads();
    if (threadIdx.x == 0) {
        float ts = 0.f, tss = 0.f;
        #pragma unroll
        for (int k = 0; k < 4; k++) { ts += sred[k]; tss += sred[4 + k]; }
        float m = ts / DD;
        float var = tss / DD - m * m;
        smean = m;
        srstd = rsqrtf(var + 1e-5f);
    }
    __syncthreads();
    float m = smean, r = srstd;
    float* orow = out + (size_t)i * DD;
    for (int d = threadIdx.x; d < DD; d += blockDim.x)
        orow[d] = (xr[d] - m) * r * w[d] + b[d];
}

// ---------------------------------------------------------------- GELU
__device__ __forceinline__ float gelu_f(float z) {
    const float c = 0.7978845608028654f; // sqrt(2/pi)
    float t = tanhf(c * (z + 0.044715f * z * z * z));
    return 0.5f * z * (1.0f + t);
}

// ---------------------------------------------------------------- weight transpose fp32[K][N] -> fp16[N][K]
__global__ void transpose_f16(const float* __restrict__ in,
                              _Float16* __restrict__ out,
                              int K, int N) {
    __shared__ _Float16 tile[64][65];
    const int k0 = blockIdx.y * 64, n0 = blockIdx.x * 64;
    const int c = threadIdx.x & 63;
    const int r4 = threadIdx.x >> 6;
    #pragma unroll
    for (int i = 0; i < 16; i++) {
        int r = r4 + i * 4;
        tile[c][r] = (_Float16)in[(size_t)(k0 + r) * N + n0 + c];
    }
    __syncthreads();
    #pragma unroll
    for (int i = 0; i < 16; i++) {
        int rn = r4 + i * 4;
        out[(size_t)(n0 + rn) * K + k0 + c] = tile[rn][c];
    }
}

__global__ void fuse_bias(const float* __restrict__ bq,
                          const float* __restrict__ bk,
                          const float* __restrict__ bv,
                          float* __restrict__ fb) {
    int i = blockIdx.x * 256 + threadIdx.x;
    if (i < 768) fb[i] = bq[i];
    else if (i < 1536) fb[i] = bk[i - 768];
    else if (i < 2304) fb[i] = bv[i - 1536];
}

// ---------------------------------------------------------------- GEMM: fp32 A x fp16 Bt^T (MFMA)
// C[M,Nn] = A[M,K] @ Bt[Nn,K]^T + bias (+gelu) (+resid). All dims mult of 128/32.
// 128x128 tile, BK=32, 4 waves 2x2. Same fragment layout as LM head (HW-verified r1).
template<int ACT, bool RES>
__global__ __launch_bounds__(256) void gemm_a32_b16(const float* __restrict__ A,
                                                    const _Float16* __restrict__ Bt,
                                                    const float* __restrict__ bias,
                                                    const float* __restrict__ resid,
                                                    float* __restrict__ C,
                                                    int M, int Nn, int K) {
    __shared__ half4_t As4[128 * 10];   // [row][40 halves]
    __shared__ half4_t Bs4[128 * 10];
    const int bm = blockIdx.y * 128;
    const int bn = blockIdx.x * 128;
    const int tid = threadIdx.x;
    const int lane = tid & 63;
    const int wave = tid >> 6;
    const int wr = (wave >> 1) * 64;
    const int wc = (wave & 1) * 64;
    const int lrow = lane & 15;
    const int kb2 = (lane >> 4) * 2;
    const int srow = tid >> 3;
    const int sc4 = tid & 7;

    float4_t acc[4][4];
    #pragma unroll
    for (int m = 0; m < 4; m++)
        #pragma unroll
        for (int n = 0; n < 4; n++)
            acc[m][n] = 0.f;

    for (int k0 = 0; k0 < K; k0 += 32) {
        #pragma unroll
        for (int p = 0; p < 4; p++) {
            int row = srow + p * 32;
            float4_t va = *(const float4_t*)(A + (size_t)(bm + row) * K + k0 + sc4 * 4);
            half4_t ha;
            ha[0] = (_Float16)va[0]; ha[1] = (_Float16)va[1];
            ha[2] = (_Float16)va[2]; ha[3] = (_Float16)va[3];
            As4[row * 10 + sc4] = ha;
        }
        #pragma unroll
        for (int i = 0; i < 2; i++) {
            int e = tid + 256 * i;
            int row = e >> 2, c8 = e & 3;
            half8_t v = *(const half8_t*)(Bt + (size_t)(bn + row) * K + k0 + c8 * 8);
            *(half8_t*)(&Bs4[row * 10 + c8 * 2]) = v;
        }
        __syncthreads();
        half8_t af[4], bf[4];
        #pragma unroll
        for (int m = 0; m < 4; m++) {
            int r = wr + m * 16 + lrow;
            half4_t lo = As4[r * 10 + kb2];
            half4_t hi = As4[r * 10 + kb2 + 1];
            af[m] = __builtin_shufflevector(lo, hi, 0, 1, 2, 3, 4, 5, 6, 7);
        }
        #pragma unroll
        for (int n = 0; n < 4; n++) {
            int r = wc + n * 16 + lrow;
            half4_t lo = Bs4[r * 10 + kb2];
            half4_t hi = Bs4[r * 10 + kb2 + 1];
            bf[n] = __builtin_shufflevector(lo, hi, 0, 1, 2, 3, 4, 5, 6, 7);
        }
        #pragma unroll
        for (int m = 0; m < 4; m++)
            #pragma unroll
            for (int n = 0; n < 4; n++)
                acc[m][n] = __builtin_amdgcn_mfma_f32_16x16x32_f16(af[m], bf[n], acc[m][n], 0, 0, 0);
        __syncthreads();
    }

    const int rbase = bm + wr + (lane >> 4) * 4;
    const int cbase = bn + wc + lrow;
    #pragma unroll
    for (int m = 0; m < 4; m++) {
        #pragma unroll
        for (int n = 0; n < 4; n++) {
            int col = cbase + n * 16;
            float bcol = bias[col];
            #pragma unroll
            for (int r = 0; r < 4; r++) {
                int row = rbase + m * 16 + r;
                float v = acc[m][n][r] + bcol;
                if (ACT == 1) v = gelu_f(v);
                if (RES) v += resid[(size_t)row * Nn + col];
                C[(size_t)row * Nn + col] = v;
            }
        }
    }
}

// ---------------------------------------------------------------- GEMM NT (LM head, f16 MFMA) — unchanged, r1-verified
__global__ __launch_bounds__(256) void gemm_nt_f16(const float* __restrict__ A,
                                                   const float* __restrict__ Bm,
                                                   float* __restrict__ C,
                                                   int M, int Nn, int K) {
    __shared__ half4_t As4[128 * 10];
    __shared__ half4_t Bs4[128 * 10];
    const int bm = blockIdx.y * 128;
    const int bn = blockIdx.x * 128;
    const int tid = threadIdx.x;
    const int lane = tid & 63;
    const int wave = tid >> 6;
    const int wr = (wave >> 1) * 64;
    const int wc = (wave & 1) * 64;
    const int lrow = lane & 15;
    const int kb2 = (lane >> 4) * 2;
    const int srow = tid >> 3;
    const int sc4 = tid & 7;

    float4_t acc[4][4];
    #pragma unroll
    for (int m = 0; m < 4; m++)
        #pragma unroll
        for (int n = 0; n < 4; n++)
            acc[m][n] = 0.f;

    for (int k0 = 0; k0 < K; k0 += 32) {
        #pragma unroll
        for (int p = 0; p < 4; p++) {
            int row = srow + p * 32;
            float4_t va = *(const float4_t*)(A + (size_t)(bm + row) * K + k0 + sc4 * 4);
            half4_t ha;
            ha[0] = (_Float16)va[0]; ha[1] = (_Float16)va[1];
            ha[2] = (_Float16)va[2]; ha[3] = (_Float16)va[3];
            As4[row * 10 + sc4] = ha;
            int gn = bn + row;
            float4_t vb = 0.f;
            if (gn < Nn)
                vb = *(const float4_t*)(Bm + (size_t)gn * K + k0 + sc4 * 4);
            half4_t hb;
            hb[0] = (_Float16)vb[0]; hb[1] = (_Float16)vb[1];
            hb[2] = (_Float16)vb[2]; hb[3] = (_Float16)vb[3];
            Bs4[row * 10 + sc4] = hb;
        }
        __syncthreads();
        half8_t af[4], bf[4];
        #pragma unroll
        for (int m = 0; m < 4; m++) {
            int r = wr + m * 16 + lrow;
            half4_t lo = As4[r * 10 + kb2];
            half4_t hi = As4[r * 10 + kb2 + 1];
            af[m] = __builtin_shufflevector(lo, hi, 0, 1, 2, 3, 4, 5, 6, 7);
        }
        #pragma unroll
        for (int n = 0; n < 4; n++) {
            int r = wc + n * 16 + lrow;
            half4_t lo = Bs4[r * 10 + kb2];
            half4_t hi = Bs4[r * 10 + kb2 + 1];
            bf[n] = __builtin_shufflevector(lo, hi, 0, 1, 2, 3, 4, 5, 6, 7);
        }
        #pragma unroll
        for (int m = 0; m < 4; m++)
            #pragma unroll
            for (int n = 0; n < 4; n++)
                acc[m][n] = __builtin_amdgcn_mfma_f32_16x16x32_f16(af[m], bf[n], acc[m][n], 0, 0, 0);
        __syncthreads();
    }

    const int rbase = bm + wr + (lane >> 4) * 4;
    const int cbase = bn + wc + lrow;
    #pragma unroll
    for (int m = 0; m < 4; m++) {
        #pragma unroll
        for (int n = 0; n < 4; n++) {
            int col = cbase + n * 16;
            if (col < Nn) {
                #pragma unroll
                for (int r = 0; r < 4; r++) {
                    int row = rbase + m * 16 + r;
                    C[(size_t)row * Nn + col] = acc[m][n][r];
                }
            }
        }
    }
}

// ---------------------------------------------------------------- flash attention (MFMA f16)
// Block = 128 thr (2 waves), owns QB=32 q-rows of one (b,h); wave w owns 16 rows.
// Per 64-key chunk: stage K[64][64] fp16 row-major + V^T[64][64] fp16 in LDS,
// QK^T (8 MFMA), in-register online softmax (row = 16-lane group, shfl_xor reduce),
// P -> LDS (wave-private) -> A-frag reads, PV (8 MFMA). Heavy q-tiles first.
#define QB 32
#define KC 64

__global__ __launch_bounds__(128) void attn_mfma(const float* __restrict__ qkv,
                                                 float* __restrict__ out) {
    const int qt = (int)(gridDim.x - 1) - (int)blockIdx.x;   // heavy blocks first
    const int qbase = qt * QB;
    const int bh = blockIdx.y;
    const int b = bh / HH, h = bh % HH;
    const int tid = threadIdx.x;
    const int lane = tid & 63;
    const int w = tid >> 6;
    const int lr = lane & 15;
    const int lg = lane >> 4;

    __shared__ _Float16 Qs[QB * 72];
    __shared__ _Float16 Ks[KC * 72];
    __shared__ _Float16 Vst[64 * 72];
    __shared__ _Float16 Ps[2 * 16 * 72];

    const size_t qoff = (size_t)b * SS * QKV_LD + h * HDIM;
    const size_t koff = qoff + 768;
    const size_t voff = qoff + 1536;

    // stage Q tile (32 x 64) fp32 -> fp16
    for (int e = tid; e < QB * 16; e += 128) {
        int row = e >> 4, f4 = e & 15;
        float4_t v4 = *(const float4_t*)(qkv + qoff + (size_t)(qbase + row) * QKV_LD + f4 * 4);
        half4_t hv;
        hv[0] = (_Float16)v4[0]; hv[1] = (_Float16)v4[1];
        hv[2] = (_Float16)v4[2]; hv[3] = (_Float16)v4[3];
        *(half4_t*)(&Qs[row * 72 + f4 * 4]) = hv;
    }
    __syncthreads();

    const int q16 = w * 16;
    half8_t aq0 = *(const half8_t*)(&Qs[(q16 + lr) * 72 + lg * 8]);
    half8_t aq1 = *(const half8_t*)(&Qs[(q16 + lr) * 72 + lg * 8 + 32]);

    float m_[4], l_[4];
    float4_t o_[4];
    #pragma unroll
    for (int r = 0; r < 4; r++) { m_[r] = -1e30f; l_[r] = 0.f; }
    #pragma unroll
    for (int n = 0; n < 4; n++) o_[n] = 0.f;

    const float scale = 0.125f;  // 1/sqrt(64)
    const int nc = ((qt + 1) * QB + KC - 1) / KC;

    for (int c = 0; c < nc; c++) {
        __syncthreads();
        // stage K chunk (row-major) and V chunk (transposed)
        for (int e = tid; e < KC * 16; e += 128) {
            int j = e >> 4, f4 = e & 15;
            size_t tok = (size_t)(c * KC + j) * QKV_LD;
            float4_t kv4 = *(const float4_t*)(qkv + koff + tok + f4 * 4);
            half4_t hk;
            hk[0] = (_Float16)kv4[0]; hk[1] = (_Float16)kv4[1];
            hk[2] = (_Float16)kv4[2]; hk[3] = (_Float16)kv4[3];
            *(half4_t*)(&Ks[j * 72 + f4 * 4]) = hk;
            float4_t vv4 = *(const float4_t*)(qkv + voff + tok + f4 * 4);
            int d0 = f4 * 4;
            Vst[(d0 + 0) * 72 + j] = (_Float16)vv4[0];
            Vst[(d0 + 1) * 72 + j] = (_Float16)vv4[1];
            Vst[(d0 + 2) * 72 + j] = (_Float16)vv4[2];
            Vst[(d0 + 3) * 72 + j] = (_Float16)vv4[3];
        }
        __syncthreads();

        // ---- QK^T: S[16q][64j]
        float4_t s_[4];
        #pragma unroll
        for (int n = 0; n < 4; n++) s_[n] = 0.f;
        #pragma unroll
        for (int n = 0; n < 4; n++) {
            half8_t bk = *(const half8_t*)(&Ks[(n * 16 + lr) * 72 + lg * 8]);
            s_[n] = __builtin_amdgcn_mfma_f32_16x16x32_f16(aq0, bk, s_[n], 0, 0, 0);
        }
        #pragma unroll
        for (int n = 0; n < 4; n++) {
            half8_t bk = *(const half8_t*)(&Ks[(n * 16 + lr) * 72 + lg * 8 + 32]);
            s_[n] = __builtin_amdgcn_mfma_f32_16x16x32_f16(aq1, bk, s_[n], 0, 0, 0);
        }

        // ---- mask + online softmax (row q = q16 + lg*4 + r, col j = n*16 + lr)
        float p_[4][4];
        #pragma unroll
        for (int r = 0; r < 4; r++) {
            int qg = qbase + q16 + lg * 4 + r;
            float sv[4];
            float cm = -1e30f;
            #pragma unroll
            for (int n = 0; n < 4; n++) {
                int jg = c * KC + n * 16 + lr;
                float v = s_[n][r] * scale;
                v = (jg <= qg) ? v : -1e30f;
                sv[n] = v;
                cm = fmaxf(cm, v);
            }
            cm = fmaxf(cm, __shfl_xor(cm, 1));
            cm = fmaxf(cm, __shfl_xor(cm, 2));
            cm = fmaxf(cm, __shfl_xor(cm, 4));
            cm = fmaxf(cm, __shfl_xor(cm, 8));
            float nm = fmaxf(m_[r], cm);
            float fac = __expf(m_[r] - nm);
            m_[r] = nm;
            float cs = 0.f;
            #pragma unroll
            for (int n = 0; n < 4; n++) {
                float p = __expf(sv[n] - nm);
                p_[n][r] = p;
                cs += p;
            }
            cs += __shfl_xor(cs, 1);
            cs += __shfl_xor(cs, 2);
            cs += __shfl_xor(cs, 4);
            cs += __shfl_xor(cs, 8);
            l_[r] = l_[r] * fac + cs;
            #pragma unroll
            for (int n = 0; n < 4; n++) o_[n][r] *= fac;
        }

        // ---- P -> LDS (wave-private) for A-fragment transpose
        _Float16* pw = &Ps[w * 16 * 72];
        #pragma unroll
        for (int n = 0; n < 4; n++)
            #pragma unroll
            for (int r = 0; r < 4; r++)
                pw[(lg * 4 + r) * 72 + n * 16 + lr] = (_Float16)p_[n][r];
        asm volatile("s_waitcnt lgkmcnt(0)" ::: "memory");
        __builtin_amdgcn_sched_barrier(0);

        // ---- PV: O[16q][64d] += P[16q][64j] @ V[64j][64d]
        {
            half8_t ap = *(const half8_t*)(&pw[lr * 72 + lg * 8]);
            #pragma unroll
            for (int n = 0; n < 4; n++) {
                half8_t bv = *(const half8_t*)(&Vst[(n * 16 + lr) * 72 + lg * 8]);
                o_[n] = __builtin_amdgcn_mfma_f32_16x16x32_f16(ap, bv, o_[n], 0, 0, 0);
            }
        }
        {
            half8_t ap = *(const half8_t*)(&pw[lr * 72 + lg * 8 + 32]);
            #pragma unroll
            for (int n = 0; n < 4; n++) {
                half8_t bv = *(const half8_t*)(&Vst[(n * 16 + lr) * 72 + lg * 8 + 32]);
                o_[n] = __builtin_amdgcn_mfma_f32_16x16x32_f16(ap, bv, o_[n], 0, 0, 0);
            }
        }
    }

    // ---- epilogue
    #pragma unroll
    for (int r = 0; r < 4; r++) {
        int qg = qbase + q16 + lg * 4 + r;
        float inv = 1.0f / l_[r];
        #pragma unroll
        for (int n = 0; n < 4; n++)
            out[(size_t)b * SS * DD + (size_t)qg * DD + h * HDIM + n * 16 + lr] = o_[n][r] * inv;
    }
}

// ---------------------------------------------------------------- launch
extern "C" void kernel_launch(void* const* d_in, const int* in_sizes, int n_in,
                              void* d_out, int out_size, void* d_ws, size_t ws_size,
                              hipStream_t stream) {
    const int*   word_idx = (const int*)  d_in[0];
    const float* tok_emb  = (const float*)d_in[1];
    const float* pos_emb  = (const float*)d_in[2];
    const float* ln1_w    = (const float*)d_in[3];
    const float* ln1_b    = (const float*)d_in[4];
    const float* wq       = (const float*)d_in[5];
    const float* bq       = (const float*)d_in[6];
    const float* wk       = (const float*)d_in[7];
    const float* bk       = (const float*)d_in[8];
    const float* wv       = (const float*)d_in[9];
    const float* bv       = (const float*)d_in[10];
    const float* wo       = (const float*)d_in[11];
    const float* bo       = (const float*)d_in[12];
    const float* ln2_w    = (const float*)d_in[13];
    const float* ln2_b    = (const float*)d_in[14];
    const float* w1       = (const float*)d_in[15];
    const float* b1       = (const float*)d_in[16];
    const float* w2       = (const float*)d_in[17];
    const float* b2       = (const float*)d_in[18];
    const float* lnf_w    = (const float*)d_in[19];
    const float* lnf_b    = (const float*)d_in[20];
    float* out = (float*)d_out;

    float* x    = (float*)d_ws;
    float* hbf  = x    + (size_t)NT * DD;
    float* qkvb = hbf  + (size_t)NT * DD;           // NT x 2304 (spans old qb/kb/vb)
    float* att  = qkvb + (size_t)NT * QKV_LD;
    float* mid  = att  + (size_t)NT * DD;           // NT x FF
    _Float16* wt = (_Float16*)(mid + (size_t)NT * FF);
    _Float16* wtqkv = wt;                            // [2304][768]
    _Float16* wtwo  = wtqkv + (size_t)QKV_LD * DD;   // [768][768]
    _Float16* wtw1  = wtwo  + (size_t)DD * DD;       // [3072][768]
    _Float16* wtw2  = wtw1  + (size_t)FF * DD;       // [768][3072]
    float* fb = (float*)(wtw2 + (size_t)DD * FF);    // [2304]

    embed_kernel<<<NT, 256, 0, stream>>>(word_idx, tok_emb, pos_emb, x);

    for (int l = 0; l < LL; l++) {
        const float* wq_l = wq + (size_t)l * DD * DD;
        const float* wk_l = wk + (size_t)l * DD * DD;
        const float* wv_l = wv + (size_t)l * DD * DD;
        const float* wo_l = wo + (size_t)l * DD * DD;
        const float* w1_l = w1 + (size_t)l * DD * FF;
        const float* w2_l = w2 + (size_t)l * FF * DD;

        // weight pre-transpose to fp16 [N][K]
        transpose_f16<<<dim3(12, 12), 256, 0, stream>>>(wq_l, wtqkv,                 DD, DD);
        transpose_f16<<<dim3(12, 12), 256, 0, stream>>>(wk_l, wtqkv + 768 * 768,     DD, DD);
        transpose_f16<<<dim3(12, 12), 256, 0, stream>>>(wv_l, wtqkv + 2 * 768 * 768, DD, DD);
        transpose_f16<<<dim3(12, 12), 256, 0, stream>>>(wo_l, wtwo, DD, DD);
        transpose_f16<<<dim3(48, 12), 256, 0, stream>>>(w1_l, wtw1, DD, FF);
        transpose_f16<<<dim3(12, 48), 256, 0, stream>>>(w2_l, wtw2, FF, DD);
        fuse_bias<<<9, 256, 0, stream>>>(bq + l * DD, bk + l * DD, bv + l * DD, fb);

        ln_kernel<<<NT, 256, 0, stream>>>(x, ln1_w + l * DD, ln1_b + l * DD, hbf);
        gemm_a32_b16<0, false><<<dim3(QKV_LD / 128, NT / 128), 256, 0, stream>>>(
            hbf, wtqkv, fb, nullptr, qkvb, NT, QKV_LD, DD);
        attn_mfma<<<dim3(SS / QB, BB * HH), 128, 0, stream>>>(qkvb, att);
        gemm_a32_b16<0, true><<<dim3(DD / 128, NT / 128), 256, 0, stream>>>(
            att, wtwo, bo + l * DD, x, x, NT, DD, DD);
        ln_kernel<<<NT, 256, 0, stream>>>(x, ln2_w + l * DD, ln2_b + l * DD, hbf);
        gemm_a32_b16<1, false><<<dim3(FF / 128, NT / 128), 256, 0, stream>>>(
            hbf, wtw1, b1 + l * FF, nullptr, mid, NT, FF, DD);
        gemm_a32_b16<0, true><<<dim3(DD / 128, NT / 128), 256, 0, stream>>>(
            mid, wtw2, b2 + l * DD, x, x, NT, DD, FF);
    }

    ln_kernel<<<NT, 256, 0, stream>>>(x, lnf_w, lnf_b, hbf);
    gemm_nt_f16<<<dim3((VV + 127) / 128, NT / 128), 256, 0, stream>>>(hbf, tok_emb, out, NT, VV, DD);
}

// Round 3
// 1284.550 us; speedup vs baseline: 5.3103x; 1.2515x over previous
//
#include <hip/hip_runtime.h>
#include <math.h>

#define VV 50257
#define VP 50304      // vocab padded to multiple of 128
#define SS 1024
#define BB 2
#define DD 768
#define HH 12
#define HDIM 64
#define FF 3072
#define LL 2
#define NT (BB*SS)     // 2048 tokens
#define QKV_LD 2304    // fused q|k|v row stride

typedef _Float16 half4_t __attribute__((ext_vector_type(4)));
typedef _Float16 half8_t __attribute__((ext_vector_type(8)));
typedef float   float4_t __attribute__((ext_vector_type(4)));

// ---------------------------------------------------------------- embedding
__global__ void embed_kernel(const int* __restrict__ idx,
                             const float* __restrict__ tok,
                             const float* __restrict__ pos,
                             float* __restrict__ x) {
    int i = blockIdx.x;
    int t = idx[i];
    int s = i % SS;
    const float* tr = tok + (size_t)t * DD;
    const float* pr = pos + (size_t)s * DD;
    float* xr = x + (size_t)i * DD;
    for (int d = threadIdx.x; d < DD; d += blockDim.x)
        xr[d] = tr[d] + pr[d];
}

// ---------------------------------------------------------------- tok_emb -> fp16, zero-padded rows
__global__ void tok_f16_kernel(const float* __restrict__ tok,
                               _Float16* __restrict__ o) {
    int r = blockIdx.x;          // [0, VP)
    int t = threadIdx.x;         // 192 threads, 1 float4 each
    half4_t h = {(_Float16)0.f, (_Float16)0.f, (_Float16)0.f, (_Float16)0.f};
    if (r < VV) {
        float4_t v = *(const float4_t*)(tok + (size_t)r * DD + t * 4);
        h[0] = (_Float16)v[0]; h[1] = (_Float16)v[1];
        h[2] = (_Float16)v[2]; h[3] = (_Float16)v[3];
    }
    *(half4_t*)(o + (size_t)r * DD + t * 4) = h;
}

// ---------------------------------------------------------------- layernorm (fp32 in, fp16 out)
__inline__ __device__ float wave_reduce_sum(float v) {
    #pragma unroll
    for (int o = 32; o > 0; o >>= 1) v += __shfl_down(v, o);
    return v;
}

__global__ void ln_kernel(const float* __restrict__ x,
                          const float* __restrict__ w,
                          const float* __restrict__ b,
                          _Float16* __restrict__ out) {
    int i = blockIdx.x;
    const float* xr = x + (size_t)i * DD;
    float s = 0.f, ss = 0.f;
    for (int d = threadIdx.x; d < DD; d += blockDim.x) {
        float v = xr[d];
        s += v; ss += v * v;
    }
    __shared__ float sred[8];
    __shared__ float smean, srstd;
    int wid = threadIdx.x >> 6, lane = threadIdx.x & 63;
    float rs = wave_reduce_sum(s);
    float rss = wave_reduce_sum(ss);
    if (lane == 0) { sred[wid] = rs; sred[4 + wid] = rss; }
    __syncthreads();
    if (threadIdx.x == 0) {
        float ts = 0.f, tss = 0.f;
        #pragma unroll
        for (int k = 0; k < 4; k++) { ts += sred[k]; tss += sred[4 + k]; }
        float m = ts / DD;
        float var = tss / DD - m * m;
        smean = m;
        srstd = rsqrtf(var + 1e-5f);
    }
    __syncthreads();
    float m = smean, r = srstd;
    _Float16* orow = out + (size_t)i * DD;
    for (int d = threadIdx.x; d < DD; d += blockDim.x)
        orow[d] = (_Float16)((xr[d] - m) * r * w[d] + b[d]);
}

// ---------------------------------------------------------------- GELU
__device__ __forceinline__ float gelu_f(float z) {
    const float c = 0.7978845608028654f; // sqrt(2/pi)
    float t = tanhf(c * (z + 0.044715f * z * z * z));
    return 0.5f * z * (1.0f + t);
}

// ---------------------------------------------------------------- weight transpose fp32[K][N] -> fp16[N][K]
__global__ void transpose_f16(const float* __restrict__ in,
                              _Float16* __restrict__ out,
                              int K, int N) {
    __shared__ _Float16 tile[64][65];
    const int k0 = blockIdx.y * 64, n0 = blockIdx.x * 64;
    const int c = threadIdx.x & 63;
    const int r4 = threadIdx.x >> 6;
    #pragma unroll
    for (int i = 0; i < 16; i++) {
        int r = r4 + i * 4;
        tile[c][r] = (_Float16)in[(size_t)(k0 + r) * N + n0 + c];
    }
    __syncthreads();
    #pragma unroll
    for (int i = 0; i < 16; i++) {
        int rn = r4 + i * 4;
        out[(size_t)(n0 + rn) * K + k0 + c] = tile[rn][c];
    }
}

__global__ void fuse_bias(const float* __restrict__ bq,
                          const float* __restrict__ bk,
                          const float* __restrict__ bv,
                          float* __restrict__ fb) {
    int i = blockIdx.x * 256 + threadIdx.x;
    if (i < 768) fb[i] = bq[i];
    else if (i < 1536) fb[i] = bk[i - 768];
    else if (i < 2304) fb[i] = bv[i - 1536];
}

// ---------------------------------------------------------------- GEMM fp16 x fp16^T (MFMA)
// C[M,Nn] = A[M,K] @ Bt[Nn,K]^T + bias (+gelu) (+fp32 resid). Dims mult of 128/32.
// 128x128 tile, BK=32, 4 waves 2x2, r1/r2-verified fragment layout.
// OUT16: write fp16; else fp32.
template<int ACT, bool RES, bool OUT16>
__global__ __launch_bounds__(256) void gemm_f16(const _Float16* __restrict__ A,
                                                const _Float16* __restrict__ Bt,
                                                const float* __restrict__ bias,
                                                const float* __restrict__ resid,
                                                void* __restrict__ Cv,
                                                int M, int Nn, int K) {
    __shared__ half4_t As4[128 * 10];   // [row][40 halves]
    __shared__ half4_t Bs4[128 * 10];
    const int bm = blockIdx.y * 128;
    const int bn = blockIdx.x * 128;
    const int tid = threadIdx.x;
    const int lane = tid & 63;
    const int wave = tid >> 6;
    const int wr = (wave >> 1) * 64;
    const int wc = (wave & 1) * 64;
    const int lrow = lane & 15;
    const int kb2 = (lane >> 4) * 2;

    float4_t acc[4][4];
    #pragma unroll
    for (int m = 0; m < 4; m++)
        #pragma unroll
        for (int n = 0; n < 4; n++)
            acc[m][n] = 0.f;

    for (int k0 = 0; k0 < K; k0 += 32) {
        #pragma unroll
        for (int i = 0; i < 2; i++) {
            int e = tid + 256 * i;
            int row = e >> 2, c8 = e & 3;
            half8_t va = *(const half8_t*)(A + (size_t)(bm + row) * K + k0 + c8 * 8);
            *(half8_t*)(&As4[row * 10 + c8 * 2]) = va;
            half8_t vb = *(const half8_t*)(Bt + (size_t)(bn + row) * K + k0 + c8 * 8);
            *(half8_t*)(&Bs4[row * 10 + c8 * 2]) = vb;
        }
        __syncthreads();
        half8_t af[4], bf[4];
        #pragma unroll
        for (int m = 0; m < 4; m++) {
            int r = wr + m * 16 + lrow;
            half4_t lo = As4[r * 10 + kb2];
            half4_t hi = As4[r * 10 + kb2 + 1];
            af[m] = __builtin_shufflevector(lo, hi, 0, 1, 2, 3, 4, 5, 6, 7);
        }
        #pragma unroll
        for (int n = 0; n < 4; n++) {
            int r = wc + n * 16 + lrow;
            half4_t lo = Bs4[r * 10 + kb2];
            half4_t hi = Bs4[r * 10 + kb2 + 1];
            bf[n] = __builtin_shufflevector(lo, hi, 0, 1, 2, 3, 4, 5, 6, 7);
        }
        #pragma unroll
        for (int m = 0; m < 4; m++)
            #pragma unroll
            for (int n = 0; n < 4; n++)
                acc[m][n] = __builtin_amdgcn_mfma_f32_16x16x32_f16(af[m], bf[n], acc[m][n], 0, 0, 0);
        __syncthreads();
    }

    const int rbase = bm + wr + (lane >> 4) * 4;
    const int cbase = bn + wc + lrow;
    #pragma unroll
    for (int m = 0; m < 4; m++) {
        #pragma unroll
        for (int n = 0; n < 4; n++) {
            int col = cbase + n * 16;
            float bcol = bias[col];
            #pragma unroll
            for (int r = 0; r < 4; r++) {
                int row = rbase + m * 16 + r;
                float v = acc[m][n][r] + bcol;
                if (ACT == 1) v = gelu_f(v);
                if (RES) v += resid[(size_t)row * Nn + col];
                if (OUT16) ((_Float16*)Cv)[(size_t)row * Nn + col] = (_Float16)v;
                else       ((float*)Cv)[(size_t)row * Nn + col] = v;
            }
        }
    }
}

// ---------------------------------------------------------------- LM head: fp16 A x fp16 tok[VP][K]^T -> fp32 C[M][VV]
__global__ __launch_bounds__(256) void gemm_lm(const _Float16* __restrict__ A,
                                               const _Float16* __restrict__ Bt,
                                               float* __restrict__ C,
                                               int M, int Nn, int K) {
    __shared__ half4_t As4[128 * 10];
    __shared__ half4_t Bs4[128 * 10];
    const int bm = blockIdx.y * 128;
    const int bn = blockIdx.x * 128;
    const int tid = threadIdx.x;
    const int lane = tid & 63;
    const int wave = tid >> 6;
    const int wr = (wave >> 1) * 64;
    const int wc = (wave & 1) * 64;
    const int lrow = lane & 15;
    const int kb2 = (lane >> 4) * 2;

    float4_t acc[4][4];
    #pragma unroll
    for (int m = 0; m < 4; m++)
        #pragma unroll
        for (int n = 0; n < 4; n++)
            acc[m][n] = 0.f;

    for (int k0 = 0; k0 < K; k0 += 32) {
        #pragma unroll
        for (int i = 0; i < 2; i++) {
            int e = tid + 256 * i;
            int row = e >> 2, c8 = e & 3;
            half8_t va = *(const half8_t*)(A + (size_t)(bm + row) * K + k0 + c8 * 8);
            *(half8_t*)(&As4[row * 10 + c8 * 2]) = va;
            half8_t vb = *(const half8_t*)(Bt + (size_t)(bn + row) * K + k0 + c8 * 8);
            *(half8_t*)(&Bs4[row * 10 + c8 * 2]) = vb;
        }
        __syncthreads();
        half8_t af[4], bf[4];
        #pragma unroll
        for (int m = 0; m < 4; m++) {
            int r = wr + m * 16 + lrow;
            half4_t lo = As4[r * 10 + kb2];
            half4_t hi = As4[r * 10 + kb2 + 1];
            af[m] = __builtin_shufflevector(lo, hi, 0, 1, 2, 3, 4, 5, 6, 7);
        }
        #pragma unroll
        for (int n = 0; n < 4; n++) {
            int r = wc + n * 16 + lrow;
            half4_t lo = Bs4[r * 10 + kb2];
            half4_t hi = Bs4[r * 10 + kb2 + 1];
            bf[n] = __builtin_shufflevector(lo, hi, 0, 1, 2, 3, 4, 5, 6, 7);
        }
        #pragma unroll
        for (int m = 0; m < 4; m++)
            #pragma unroll
            for (int n = 0; n < 4; n++)
                acc[m][n] = __builtin_amdgcn_mfma_f32_16x16x32_f16(af[m], bf[n], acc[m][n], 0, 0, 0);
        __syncthreads();
    }

    const int rbase = bm + wr + (lane >> 4) * 4;
    const int cbase = bn + wc + lrow;
    #pragma unroll
    for (int m = 0; m < 4; m++) {
        #pragma unroll
        for (int n = 0; n < 4; n++) {
            int col = cbase + n * 16;
            if (col < Nn) {
                #pragma unroll
                for (int r = 0; r < 4; r++) {
                    int row = rbase + m * 16 + r;
                    C[(size_t)row * Nn + col] = acc[m][n][r];
                }
            }
        }
    }
}

// ---------------------------------------------------------------- flash attention (MFMA f16, fp16 qkv in, fp16 out)
#define QB 32
#define KC 64

__global__ __launch_bounds__(128) void attn_mfma(const _Float16* __restrict__ qkv,
                                                 _Float16* __restrict__ outh) {
    const int qt = (int)(gridDim.x - 1) - (int)blockIdx.x;   // heavy blocks first
    const int qbase = qt * QB;
    const int bh = blockIdx.y;
    const int b = bh / HH, h = bh % HH;
    const int tid = threadIdx.x;
    const int lane = tid & 63;
    const int w = tid >> 6;
    const int lr = lane & 15;
    const int lg = lane >> 4;

    __shared__ _Float16 Ks[KC * 72];
    __shared__ _Float16 Vst[64 * 72];
    __shared__ _Float16 Ps[2 * 16 * 72];

    const size_t qoff = (size_t)b * SS * QKV_LD + h * HDIM;
    const size_t koff = qoff + 768;
    const size_t voff = qoff + 1536;

    // Q fragments straight from global (fp16, 16B aligned)
    const int q16 = w * 16;
    const int qrow = qbase + q16 + lr;
    half8_t aq0 = *(const half8_t*)(qkv + qoff + (size_t)qrow * QKV_LD + lg * 8);
    half8_t aq1 = *(const half8_t*)(qkv + qoff + (size_t)qrow * QKV_LD + lg * 8 + 32);

    float m_[4], l_[4];
    float4_t o_[4];
    #pragma unroll
    for (int r = 0; r < 4; r++) { m_[r] = -1e30f; l_[r] = 0.f; }
    #pragma unroll
    for (int n = 0; n < 4; n++) o_[n] = 0.f;

    const float scale = 0.125f;  // 1/sqrt(64)
    const int nc = ((qt + 1) * QB + KC - 1) / KC;

    for (int c = 0; c < nc; c++) {
        __syncthreads();
        // stage K (row-major) + V (transposed), fp16 copies
        for (int e = tid; e < KC * 8; e += 128) {
            int j = e >> 3, u = e & 7;
            size_t tok = (size_t)(c * KC + j) * QKV_LD;
            *(half8_t*)(&Ks[j * 72 + u * 8]) = *(const half8_t*)(qkv + koff + tok + u * 8);
            half8_t vv = *(const half8_t*)(qkv + voff + tok + u * 8);
            int d0 = u * 8;
            #pragma unroll
            for (int q = 0; q < 8; q++)
                Vst[(d0 + q) * 72 + j] = vv[q];
        }
        __syncthreads();

        // ---- QK^T: S[16q][64j]
        float4_t s_[4];
        #pragma unroll
        for (int n = 0; n < 4; n++) s_[n] = 0.f;
        #pragma unroll
        for (int n = 0; n < 4; n++) {
            half8_t bk = *(const half8_t*)(&Ks[(n * 16 + lr) * 72 + lg * 8]);
            s_[n] = __builtin_amdgcn_mfma_f32_16x16x32_f16(aq0, bk, s_[n], 0, 0, 0);
        }
        #pragma unroll
        for (int n = 0; n < 4; n++) {
            half8_t bk = *(const half8_t*)(&Ks[(n * 16 + lr) * 72 + lg * 8 + 32]);
            s_[n] = __builtin_amdgcn_mfma_f32_16x16x32_f16(aq1, bk, s_[n], 0, 0, 0);
        }

        // ---- mask + online softmax (row q = q16 + lg*4 + r, col j = n*16 + lr)
        float p_[4][4];
        #pragma unroll
        for (int r = 0; r < 4; r++) {
            int qg = qbase + q16 + lg * 4 + r;
            float sv[4];
            float cm = -1e30f;
            #pragma unroll
            for (int n = 0; n < 4; n++) {
                int jg = c * KC + n * 16 + lr;
                float v = s_[n][r] * scale;
                v = (jg <= qg) ? v : -1e30f;
                sv[n] = v;
                cm = fmaxf(cm, v);
            }
            cm = fmaxf(cm, __shfl_xor(cm, 1));
            cm = fmaxf(cm, __shfl_xor(cm, 2));
            cm = fmaxf(cm, __shfl_xor(cm, 4));
            cm = fmaxf(cm, __shfl_xor(cm, 8));
            float nm = fmaxf(m_[r], cm);
            float fac = __expf(m_[r] - nm);
            m_[r] = nm;
            float cs = 0.f;
            #pragma unroll
            for (int n = 0; n < 4; n++) {
                float p = __expf(sv[n] - nm);
                p_[n][r] = p;
                cs += p;
            }
            cs += __shfl_xor(cs, 1);
            cs += __shfl_xor(cs, 2);
            cs += __shfl_xor(cs, 4);
            cs += __shfl_xor(cs, 8);
            l_[r] = l_[r] * fac + cs;
            #pragma unroll
            for (int n = 0; n < 4; n++) o_[n][r] *= fac;
        }

        // ---- P -> LDS (wave-private) for A-fragment transpose
        _Float16* pw = &Ps[w * 16 * 72];
        #pragma unroll
        for (int n = 0; n < 4; n++)
            #pragma unroll
            for (int r = 0; r < 4; r++)
                pw[(lg * 4 + r) * 72 + n * 16 + lr] = (_Float16)p_[n][r];
        asm volatile("s_waitcnt lgkmcnt(0)" ::: "memory");
        __builtin_amdgcn_sched_barrier(0);

        // ---- PV: O[16q][64d] += P[16q][64j] @ V[64j][64d]
        {
            half8_t ap = *(const half8_t*)(&pw[lr * 72 + lg * 8]);
            #pragma unroll
            for (int n = 0; n < 4; n++) {
                half8_t bv = *(const half8_t*)(&Vst[(n * 16 + lr) * 72 + lg * 8]);
                o_[n] = __builtin_amdgcn_mfma_f32_16x16x32_f16(ap, bv, o_[n], 0, 0, 0);
            }
        }
        {
            half8_t ap = *(const half8_t*)(&pw[lr * 72 + lg * 8 + 32]);
            #pragma unroll
            for (int n = 0; n < 4; n++) {
                half8_t bv = *(const half8_t*)(&Vst[(n * 16 + lr) * 72 + lg * 8 + 32]);
                o_[n] = __builtin_amdgcn_mfma_f32_16x16x32_f16(ap, bv, o_[n], 0, 0, 0);
            }
        }
    }

    // ---- epilogue (fp16 out)
    #pragma unroll
    for (int r = 0; r < 4; r++) {
        int qg = qbase + q16 + lg * 4 + r;
        float inv = 1.0f / l_[r];
        #pragma unroll
        for (int n = 0; n < 4; n++)
            outh[(size_t)b * SS * DD + (size_t)qg * DD + h * HDIM + n * 16 + lr] =
                (_Float16)(o_[n][r] * inv);
    }
}

// ---------------------------------------------------------------- launch
extern "C" void kernel_launch(void* const* d_in, const int* in_sizes, int n_in,
                              void* d_out, int out_size, void* d_ws, size_t ws_size,
                              hipStream_t stream) {
    const int*   word_idx = (const int*)  d_in[0];
    const float* tok_emb  = (const float*)d_in[1];
    const float* pos_emb  = (const float*)d_in[2];
    const float* ln1_w    = (const float*)d_in[3];
    const float* ln1_b    = (const float*)d_in[4];
    const float* wq       = (const float*)d_in[5];
    const float* bq       = (const float*)d_in[6];
    const float* wk       = (const float*)d_in[7];
    const float* bk       = (const float*)d_in[8];
    const float* wv       = (const float*)d_in[9];
    const float* bv       = (const float*)d_in[10];
    const float* wo       = (const float*)d_in[11];
    const float* bo       = (const float*)d_in[12];
    const float* ln2_w    = (const float*)d_in[13];
    const float* ln2_b    = (const float*)d_in[14];
    const float* w1       = (const float*)d_in[15];
    const float* b1       = (const float*)d_in[16];
    const float* w2       = (const float*)d_in[17];
    const float* b2       = (const float*)d_in[18];
    const float* lnf_w    = (const float*)d_in[19];
    const float* lnf_b    = (const float*)d_in[20];
    float* out = (float*)d_out;

    float* x        = (float*)d_ws;                          // NT x DD f32
    _Float16* hbf   = (_Float16*)(x + (size_t)NT * DD);      // NT x DD
    _Float16* qkvb  = hbf  + (size_t)NT * DD;                // NT x 2304
    _Float16* att   = qkvb + (size_t)NT * QKV_LD;            // NT x DD
    _Float16* mid   = att  + (size_t)NT * DD;                // NT x FF
    _Float16* wtqkv = mid  + (size_t)NT * FF;                // [2304][768]
    _Float16* wtwo  = wtqkv + (size_t)QKV_LD * DD;           // [768][768]
    _Float16* wtw1  = wtwo  + (size_t)DD * DD;               // [3072][768]
    _Float16* wtw2  = wtw1  + (size_t)FF * DD;               // [768][3072]
    _Float16* tokf  = wtw2  + (size_t)DD * FF;               // [VP][768]
    float* fb = (float*)(tokf + (size_t)VP * DD);            // [2304]

    embed_kernel<<<NT, 256, 0, stream>>>(word_idx, tok_emb, pos_emb, x);
    tok_f16_kernel<<<VP, 192, 0, stream>>>(tok_emb, tokf);

    for (int l = 0; l < LL; l++) {
        const float* wq_l = wq + (size_t)l * DD * DD;
        const float* wk_l = wk + (size_t)l * DD * DD;
        const float* wv_l = wv + (size_t)l * DD * DD;
        const float* wo_l = wo + (size_t)l * DD * DD;
        const float* w1_l = w1 + (size_t)l * DD * FF;
        const float* w2_l = w2 + (size_t)l * FF * DD;

        transpose_f16<<<dim3(12, 12), 256, 0, stream>>>(wq_l, wtqkv,                 DD, DD);
        transpose_f16<<<dim3(12, 12), 256, 0, stream>>>(wk_l, wtqkv + 768 * 768,     DD, DD);
        transpose_f16<<<dim3(12, 12), 256, 0, stream>>>(wv_l, wtqkv + 2 * 768 * 768, DD, DD);
        transpose_f16<<<dim3(12, 12), 256, 0, stream>>>(wo_l, wtwo, DD, DD);
        transpose_f16<<<dim3(48, 12), 256, 0, stream>>>(w1_l, wtw1, DD, FF);
        transpose_f16<<<dim3(12, 48), 256, 0, stream>>>(w2_l, wtw2, FF, DD);
        fuse_bias<<<9, 256, 0, stream>>>(bq + l * DD, bk + l * DD, bv + l * DD, fb);

        ln_kernel<<<NT, 256, 0, stream>>>(x, ln1_w + l * DD, ln1_b + l * DD, hbf);
        gemm_f16<0, false, true><<<dim3(QKV_LD / 128, NT / 128), 256, 0, stream>>>(
            hbf, wtqkv, fb, nullptr, qkvb, NT, QKV_LD, DD);
        attn_mfma<<<dim3(SS / QB, BB * HH), 128, 0, stream>>>(qkvb, att);
        gemm_f16<0, true, false><<<dim3(DD / 128, NT / 128), 256, 0, stream>>>(
            att, wtwo, bo + l * DD, x, x, NT, DD, DD);
        ln_kernel<<<NT, 256, 0, stream>>>(x, ln2_w + l * DD, ln2_b + l * DD, hbf);
        gemm_f16<1, false, true><<<dim3(FF / 128, NT / 128), 256, 0, stream>>>(
            hbf, wtw1, b1 + l * FF, nullptr, mid, NT, FF, DD);
        gemm_f16<0, true, false><<<dim3(DD / 128, NT / 128), 256, 0, stream>>>(
            mid, wtw2, b2 + l * DD, x, x, NT, DD, FF);
    }

    ln_kernel<<<NT, 256, 0, stream>>>(x, lnf_w, lnf_b, hbf);
    gemm_lm<<<dim3(VP / 128, NT / 128), 256, 0, stream>>>(hbf, tokf, out, NT, VV, DD);
}